// Round 1
// baseline (844.599 us; speedup 1.0000x reference)
//
#include <hip/hip_runtime.h>

typedef __bf16 bf16x8 __attribute__((ext_vector_type(8)));
typedef float f32x4 __attribute__((ext_vector_type(4)));
typedef unsigned short u16;
typedef unsigned int u32;

#define BB 4
#define NNCTX 2048
#define CCH 384
#define NHEAD 6
#define DHEAD 64
#define HIDDIM 1536

__device__ __forceinline__ u16 f2bf(float f){
  u32 u = __builtin_bit_cast(u32, f);
  u = u + 0x7fffu + ((u >> 16) & 1u);
  return (u16)(u >> 16);
}
__device__ __forceinline__ float bf2f(u16 h){
  u32 u = ((u32)h) << 16;
  return __builtin_bit_cast(float, u);
}

__global__ __launch_bounds__(256) void cast_kernel(const float* __restrict__ in, u16* __restrict__ out, int n){
  int i = blockIdx.x * 256 + threadIdx.x;
  if (i < n) out[i] = f2bf(in[i]);
}

// One block per row (C=384), 128 threads: each handles 3 elements.
__global__ __launch_bounds__(128) void ln_kernel(const float* __restrict__ x, const float* __restrict__ g,
                                                 const float* __restrict__ bb, u16* __restrict__ out){
  int row = blockIdx.x, t = threadIdx.x;
  const float* xr = x + (size_t)row * CCH;
  float v0 = xr[t], v1 = xr[t + 128], v2 = xr[t + 256];
  float s = v0 + v1 + v2;
  float q = v0 * v0 + v1 * v1 + v2 * v2;
  #pragma unroll
  for (int o = 32; o; o >>= 1){ s += __shfl_down(s, o); q += __shfl_down(q, o); }
  __shared__ float sh[4];
  if ((t & 63) == 0){ int w = t >> 6; sh[w * 2] = s; sh[w * 2 + 1] = q; }
  __syncthreads();
  float sum = sh[0] + sh[2], ssq = sh[1] + sh[3];
  float mu = sum * (1.0f / 384.0f);
  float rstd = rsqrtf(ssq * (1.0f / 384.0f) - mu * mu + 1e-5f);
  size_t base = (size_t)row * CCH;
  out[base + t]       = f2bf((v0 - mu) * rstd * g[t]       + bb[t]);
  out[base + t + 128] = f2bf((v1 - mu) * rstd * g[t + 128] + bb[t + 128]);
  out[base + t + 256] = f2bf((v2 - mu) * rstd * g[t + 256] + bb[t + 256]);
}

// Tiled bf16 MFMA GEMM: C[M,Nn] = A[M,K] @ B[K,Nn]. 64x64 tile, 256 threads (4 waves, 2x2 of 32x32).
// EPI 0: store bf16. EPI 1: fp32 out = resid + acc + bias. EPI 2: bf16 out = gelu(acc + bias).
template<int EPI>
__global__ __launch_bounds__(256) void gemm_bf16(const u16* __restrict__ A, const u16* __restrict__ Bm,
    int K, int Nn, u16* __restrict__ outb, const float* __restrict__ bias,
    const float* __restrict__ resid, float* __restrict__ outf)
{
  __shared__ u16 As[64][72];   // [m][k], pad 8 -> row stride 144B (2-way bank alias, free)
  __shared__ u16 Bs[64][72];   // [n][k] transposed
  int t = threadIdx.x;
  int bm = blockIdx.y * 64, bn = blockIdx.x * 64;
  int l = t & 63, w = t >> 6;
  int wm = (w >> 1) * 32, wn = (w & 1) * 32;
  f32x4 acc[2][2] = {};
  int ar0 = t >> 3, ac0 = (t & 7) * 8;   // 8-bf16 chunks; rows 0..31 and 32..63
  for (int k0 = 0; k0 < K; k0 += 64){
    __syncthreads();
    *(uint4*)&As[ar0][ac0]      = *(const uint4*)&A[(size_t)(bm + ar0) * K + k0 + ac0];
    *(uint4*)&As[ar0 + 32][ac0] = *(const uint4*)&A[(size_t)(bm + ar0 + 32) * K + k0 + ac0];
    uint4 b0 = *(const uint4*)&Bm[(size_t)(k0 + ar0) * Nn + bn + ac0];
    uint4 b1 = *(const uint4*)&Bm[(size_t)(k0 + ar0 + 32) * Nn + bn + ac0];
    const u16* p0 = (const u16*)&b0;
    const u16* p1 = (const u16*)&b1;
    #pragma unroll
    for (int j = 0; j < 8; j++){ Bs[ac0 + j][ar0] = p0[j]; Bs[ac0 + j][ar0 + 32] = p1[j]; }
    __syncthreads();
    #pragma unroll
    for (int ks = 0; ks < 2; ks++){
      int kb = ks * 32 + (l >> 4) * 8;
      bf16x8 a0  = *(const bf16x8*)&As[wm + (l & 15)][kb];
      bf16x8 a1  = *(const bf16x8*)&As[wm + 16 + (l & 15)][kb];
      bf16x8 bb0 = *(const bf16x8*)&Bs[wn + (l & 15)][kb];
      bf16x8 bb1 = *(const bf16x8*)&Bs[wn + 16 + (l & 15)][kb];
      acc[0][0] = __builtin_amdgcn_mfma_f32_16x16x32_bf16(a0, bb0, acc[0][0], 0, 0, 0);
      acc[0][1] = __builtin_amdgcn_mfma_f32_16x16x32_bf16(a0, bb1, acc[0][1], 0, 0, 0);
      acc[1][0] = __builtin_amdgcn_mfma_f32_16x16x32_bf16(a1, bb0, acc[1][0], 0, 0, 0);
      acc[1][1] = __builtin_amdgcn_mfma_f32_16x16x32_bf16(a1, bb1, acc[1][1], 0, 0, 0);
    }
  }
  #pragma unroll
  for (int mi = 0; mi < 2; mi++)
  #pragma unroll
  for (int ni = 0; ni < 2; ni++)
  #pragma unroll
  for (int r = 0; r < 4; r++){
    int row = bm + wm + mi * 16 + ((l >> 4) << 2) + r;
    int col = bn + wn + ni * 16 + (l & 15);
    size_t idx = (size_t)row * Nn + col;
    float v = acc[mi][ni][r];
    if (EPI == 0){
      outb[idx] = f2bf(v);
    } else if (EPI == 1){
      outf[idx] = resid[idx] + v + bias[col];
    } else {
      v += bias[col];
      v = 0.5f * v * (1.0f + erff(v * 0.70710678118f));
      outb[idx] = f2bf(v);
    }
  }
}

// Vector-fp32 flash attention. Block = 256 threads handles one (b,h) head and 16 query rows.
// Online softmax over 32 key-tiles of 64 keys.
__global__ __launch_bounds__(256) void attn_fwd(const u16* __restrict__ qkv, u16* __restrict__ obuf){
  __shared__ float Qs[16][68];
  __shared__ float Ks[64][68];
  __shared__ float Vs[64][68];
  __shared__ float Ps[16][68];
  int t = threadIdx.x;
  int bh = blockIdx.y;
  int b = bh / NHEAD, h = bh % NHEAD;
  int n0 = blockIdx.x * 16;
  int qi = t >> 4, l16 = t & 15;

  // Stage Q (scaled by 1/sqrt(D))
  {
    const u16* qp = qkv + ((size_t)(b * NNCTX + n0 + qi)) * 1152 + h * 64 + l16 * 4;
    ushort4 qv = *(const ushort4*)qp;
    Qs[qi][l16 * 4 + 0] = bf2f(qv.x) * 0.125f;
    Qs[qi][l16 * 4 + 1] = bf2f(qv.y) * 0.125f;
    Qs[qi][l16 * 4 + 2] = bf2f(qv.z) * 0.125f;
    Qs[qi][l16 * 4 + 3] = bf2f(qv.w) * 0.125f;
  }
  float oa0 = 0.f, oa1 = 0.f, oa2 = 0.f, oa3 = 0.f;
  float m_r = -__builtin_inff(), l_r = 0.f;
  int kr = t >> 2, dblk = (t & 3) * 16;
  const size_t kvbase = (size_t)(b * NNCTX) * 1152 + h * 64;

  for (int kt = 0; kt < 32; kt++){
    __syncthreads();
    { // stage K and V tiles [64][64]
      const u16* kp = qkv + kvbase + (size_t)(kt * 64 + kr) * 1152 + 384 + dblk;
      uint4 ka = *(const uint4*)kp;
      uint4 kb = *(const uint4*)(kp + 8);
      const u16* pa = (const u16*)&ka; const u16* pb = (const u16*)&kb;
      #pragma unroll
      for (int j = 0; j < 8; j++){ Ks[kr][dblk + j] = bf2f(pa[j]); Ks[kr][dblk + 8 + j] = bf2f(pb[j]); }
      const u16* vp = kp + 384;
      uint4 va = *(const uint4*)vp;
      uint4 vb = *(const uint4*)(vp + 8);
      const u16* pc = (const u16*)&va; const u16* pd = (const u16*)&vb;
      #pragma unroll
      for (int j = 0; j < 8; j++){ Vs[kr][dblk + j] = bf2f(pc[j]); Vs[kr][dblk + 8 + j] = bf2f(pd[j]); }
    }
    __syncthreads();
    // S: thread (qi,l16) computes keys kj = l16 + 16*jj
    float s0 = 0.f, s1 = 0.f, s2 = 0.f, s3 = 0.f;
    #pragma unroll
    for (int dd = 0; dd < 16; dd++){
      float4 qv = *(const float4*)&Qs[qi][dd * 4];
      float4 k0 = *(const float4*)&Ks[l16     ][dd * 4];
      float4 k1 = *(const float4*)&Ks[l16 + 16][dd * 4];
      float4 k2 = *(const float4*)&Ks[l16 + 32][dd * 4];
      float4 k3 = *(const float4*)&Ks[l16 + 48][dd * 4];
      s0 += qv.x * k0.x + qv.y * k0.y + qv.z * k0.z + qv.w * k0.w;
      s1 += qv.x * k1.x + qv.y * k1.y + qv.z * k1.z + qv.w * k1.w;
      s2 += qv.x * k2.x + qv.y * k2.y + qv.z * k2.z + qv.w * k2.w;
      s3 += qv.x * k3.x + qv.y * k3.y + qv.z * k3.z + qv.w * k3.w;
    }
    float mt = fmaxf(fmaxf(s0, s1), fmaxf(s2, s3));
    mt = fmaxf(mt, __shfl_xor(mt, 1));
    mt = fmaxf(mt, __shfl_xor(mt, 2));
    mt = fmaxf(mt, __shfl_xor(mt, 4));
    mt = fmaxf(mt, __shfl_xor(mt, 8));
    float m_new = fmaxf(m_r, mt);
    float p0 = __expf(s0 - m_new), p1 = __expf(s1 - m_new);
    float p2 = __expf(s2 - m_new), p3 = __expf(s3 - m_new);
    float ps = p0 + p1 + p2 + p3;
    ps += __shfl_xor(ps, 1);
    ps += __shfl_xor(ps, 2);
    ps += __shfl_xor(ps, 4);
    ps += __shfl_xor(ps, 8);
    float alpha = __expf(m_r - m_new);
    l_r = l_r * alpha + ps;
    m_r = m_new;
    oa0 *= alpha; oa1 *= alpha; oa2 *= alpha; oa3 *= alpha;
    Ps[qi][l16]      = p0;
    Ps[qi][l16 + 16] = p1;
    Ps[qi][l16 + 32] = p2;
    Ps[qi][l16 + 48] = p3;
    __syncthreads();
    // PV: thread (qi,l16) owns O[qi][l16*4 .. +3]
    #pragma unroll 4
    for (int kj = 0; kj < 64; kj++){
      float pv = Ps[qi][kj];
      float4 vv = *(const float4*)&Vs[kj][l16 * 4];
      oa0 += pv * vv.x; oa1 += pv * vv.y; oa2 += pv * vv.z; oa3 += pv * vv.w;
    }
  }
  float inv = 1.0f / l_r;
  ushort4 ov;
  ov.x = f2bf(oa0 * inv); ov.y = f2bf(oa1 * inv);
  ov.z = f2bf(oa2 * inv); ov.w = f2bf(oa3 * inv);
  *(ushort4*)(obuf + (size_t)(b * NNCTX + n0 + qi) * CCH + h * 64 + l16 * 4) = ov;
}

extern "C" void kernel_launch(void* const* d_in, const int* in_sizes, int n_in,
                              void* d_out, int out_size, void* d_ws, size_t ws_size,
                              hipStream_t stream){
  const float* x      = (const float*)d_in[0];
  const float* ln1_g  = (const float*)d_in[1];
  const float* ln1_b  = (const float*)d_in[2];
  const float* w_qkv  = (const float*)d_in[3];
  const float* w_proj = (const float*)d_in[4];
  const float* b_proj = (const float*)d_in[5];
  const float* ln2_g  = (const float*)d_in[6];
  const float* ln2_b  = (const float*)d_in[7];
  const float* w_fc1  = (const float*)d_in[8];
  const float* b_fc1  = (const float*)d_in[9];
  const float* w_fc2  = (const float*)d_in[10];
  const float* b_fc2  = (const float*)d_in[11];
  float* out = (float*)d_out;

  u16* ws = (u16*)d_ws;
  u16* wqkv_bf  = ws;                       // 384*1152 = 442368
  u16* wproj_bf = wqkv_bf + 442368;         // 384*384  = 147456
  u16* wfc1_bf  = wproj_bf + 147456;        // 384*1536 = 589824
  u16* wfc2_bf  = wfc1_bf + 589824;         // 1536*384 = 589824
  u16* h_bf     = wfc2_bf + 589824;         // 8192*384 = 3145728 (reused as h2)
  u16* qkv_bf   = h_bf + 3145728;           // 8192*1152 = 9437184
  u16* o_bf     = qkv_bf + 9437184;         // 8192*384 = 3145728
  u16* m_bf     = qkv_bf;                   // 8192*1536 = 12582912 (reuses qkv+o after proj)

  cast_kernel<<<(442368 + 255) / 256, 256, 0, stream>>>(w_qkv,  wqkv_bf,  442368);
  cast_kernel<<<(147456 + 255) / 256, 256, 0, stream>>>(w_proj, wproj_bf, 147456);
  cast_kernel<<<(589824 + 255) / 256, 256, 0, stream>>>(w_fc1,  wfc1_bf,  589824);
  cast_kernel<<<(589824 + 255) / 256, 256, 0, stream>>>(w_fc2,  wfc2_bf,  589824);

  // LN1 -> h (bf16)
  ln_kernel<<<8192, 128, 0, stream>>>(x, ln1_g, ln1_b, h_bf);
  // QKV = h @ w_qkv  [8192,1152] bf16
  gemm_bf16<0><<<dim3(18, 128), 256, 0, stream>>>(h_bf, wqkv_bf, 384, 1152, qkv_bf, nullptr, nullptr, nullptr);
  // attention -> o (bf16)
  attn_fwd<<<dim3(128, 24), 256, 0, stream>>>(qkv_bf, o_bf);
  // x1 = x + o @ w_proj + b_proj  (fp32, into d_out)
  gemm_bf16<1><<<dim3(6, 128), 256, 0, stream>>>(o_bf, wproj_bf, 384, 384, nullptr, b_proj, x, out);
  // LN2 -> h2 (bf16, reuse h)
  ln_kernel<<<8192, 128, 0, stream>>>(out, ln2_g, ln2_b, h_bf);
  // m = gelu(h2 @ w_fc1 + b_fc1)  bf16
  gemm_bf16<2><<<dim3(24, 128), 256, 0, stream>>>(h_bf, wfc1_bf, 384, 1536, m_bf, b_fc1, nullptr, nullptr);
  // out = x1 + m @ w_fc2 + b_fc2  (fp32, in-place on d_out)
  gemm_bf16<1><<<dim3(6, 128), 256, 0, stream>>>(m_bf, wfc2_bf, 1536, 384, nullptr, b_fc2, out, out);
}

// Round 2
// 294.295 us; speedup vs baseline: 2.8699x; 2.8699x over previous
//
#include <hip/hip_runtime.h>

typedef __bf16 bf16x8 __attribute__((ext_vector_type(8)));
typedef float f32x4 __attribute__((ext_vector_type(4)));
typedef unsigned short u16;
typedef unsigned int u32;

#define BB 4
#define NNCTX 2048
#define CCH 384
#define NHEAD 6
#define DHEAD 64
#define HIDDIM 1536

__device__ __forceinline__ u16 f2bf(float f){
  u32 u = __builtin_bit_cast(u32, f);
  u = u + 0x7fffu + ((u >> 16) & 1u);
  return (u16)(u >> 16);
}
__device__ __forceinline__ float bf2f(u16 h){
  u32 u = ((u32)h) << 16;
  return __builtin_bit_cast(float, u);
}

union U8 { uint4 u; u16 s[8]; bf16x8 v; };

__global__ __launch_bounds__(256) void cast_kernel(const float* __restrict__ in, u16* __restrict__ out, int n){
  int i = blockIdx.x * 256 + threadIdx.x;
  if (i < n) out[i] = f2bf(in[i]);
}

// One block per row (C=384), 128 threads: each handles 3 elements.
__global__ __launch_bounds__(128) void ln_kernel(const float* __restrict__ x, const float* __restrict__ g,
                                                 const float* __restrict__ bb, u16* __restrict__ out){
  int row = blockIdx.x, t = threadIdx.x;
  const float* xr = x + (size_t)row * CCH;
  float v0 = xr[t], v1 = xr[t + 128], v2 = xr[t + 256];
  float s = v0 + v1 + v2;
  float q = v0 * v0 + v1 * v1 + v2 * v2;
  #pragma unroll
  for (int o = 32; o; o >>= 1){ s += __shfl_down(s, o); q += __shfl_down(q, o); }
  __shared__ float sh[4];
  if ((t & 63) == 0){ int w = t >> 6; sh[w * 2] = s; sh[w * 2 + 1] = q; }
  __syncthreads();
  float sum = sh[0] + sh[2], ssq = sh[1] + sh[3];
  float mu = sum * (1.0f / 384.0f);
  float rstd = rsqrtf(ssq * (1.0f / 384.0f) - mu * mu + 1e-5f);
  size_t base = (size_t)row * CCH;
  out[base + t]       = f2bf((v0 - mu) * rstd * g[t]       + bb[t]);
  out[base + t + 128] = f2bf((v1 - mu) * rstd * g[t + 128] + bb[t + 128]);
  out[base + t + 256] = f2bf((v2 - mu) * rstd * g[t + 256] + bb[t + 256]);
}

// Tiled bf16 MFMA GEMM: C[M,Nn] = A[M,K] @ B[K,Nn]. 64x64 tile, 256 threads (4 waves, 2x2 of 32x32).
// EPI 0: store bf16. EPI 1: fp32 out = resid + acc + bias. EPI 2: bf16 out = gelu(acc + bias).
template<int EPI>
__global__ __launch_bounds__(256) void gemm_bf16(const u16* __restrict__ A, const u16* __restrict__ Bm,
    int K, int Nn, u16* __restrict__ outb, const float* __restrict__ bias,
    const float* __restrict__ resid, float* __restrict__ outf)
{
  __shared__ u16 As[64][72];   // [m][k], pad 8 -> row stride 144B (2-way bank alias, free)
  __shared__ u16 Bs[64][72];   // [n][k] transposed
  int t = threadIdx.x;
  int bm = blockIdx.y * 64, bn = blockIdx.x * 64;
  int l = t & 63, w = t >> 6;
  int wm = (w >> 1) * 32, wn = (w & 1) * 32;
  f32x4 acc[2][2] = {};
  int ar0 = t >> 3, ac0 = (t & 7) * 8;   // 8-bf16 chunks; rows 0..31 and 32..63
  for (int k0 = 0; k0 < K; k0 += 64){
    __syncthreads();
    *(uint4*)&As[ar0][ac0]      = *(const uint4*)&A[(size_t)(bm + ar0) * K + k0 + ac0];
    *(uint4*)&As[ar0 + 32][ac0] = *(const uint4*)&A[(size_t)(bm + ar0 + 32) * K + k0 + ac0];
    uint4 b0 = *(const uint4*)&Bm[(size_t)(k0 + ar0) * Nn + bn + ac0];
    uint4 b1 = *(const uint4*)&Bm[(size_t)(k0 + ar0 + 32) * Nn + bn + ac0];
    const u16* p0 = (const u16*)&b0;
    const u16* p1 = (const u16*)&b1;
    #pragma unroll
    for (int j = 0; j < 8; j++){ Bs[ac0 + j][ar0] = p0[j]; Bs[ac0 + j][ar0 + 32] = p1[j]; }
    __syncthreads();
    #pragma unroll
    for (int ks = 0; ks < 2; ks++){
      int kb = ks * 32 + (l >> 4) * 8;
      bf16x8 a0  = *(const bf16x8*)&As[wm + (l & 15)][kb];
      bf16x8 a1  = *(const bf16x8*)&As[wm + 16 + (l & 15)][kb];
      bf16x8 bb0 = *(const bf16x8*)&Bs[wn + (l & 15)][kb];
      bf16x8 bb1 = *(const bf16x8*)&Bs[wn + 16 + (l & 15)][kb];
      acc[0][0] = __builtin_amdgcn_mfma_f32_16x16x32_bf16(a0, bb0, acc[0][0], 0, 0, 0);
      acc[0][1] = __builtin_amdgcn_mfma_f32_16x16x32_bf16(a0, bb1, acc[0][1], 0, 0, 0);
      acc[1][0] = __builtin_amdgcn_mfma_f32_16x16x32_bf16(a1, bb0, acc[1][0], 0, 0, 0);
      acc[1][1] = __builtin_amdgcn_mfma_f32_16x16x32_bf16(a1, bb1, acc[1][1], 0, 0, 0);
    }
  }
  #pragma unroll
  for (int mi = 0; mi < 2; mi++)
  #pragma unroll
  for (int ni = 0; ni < 2; ni++)
  #pragma unroll
  for (int r = 0; r < 4; r++){
    int row = bm + wm + mi * 16 + ((l >> 4) << 2) + r;
    int col = bn + wn + ni * 16 + (l & 15);
    size_t idx = (size_t)row * Nn + col;
    float v = acc[mi][ni][r];
    if (EPI == 0){
      outb[idx] = f2bf(v);
    } else if (EPI == 1){
      outf[idx] = resid[idx] + v + bias[col];
    } else {
      v += bias[col];
      v = 0.5f * v * (1.0f + erff(v * 0.70710678118f));
      outb[idx] = f2bf(v);
    }
  }
}

// MFMA flash attention. Block = 256 threads (4 waves) = one (b,h), 64 q-rows.
// Wave w owns q-rows q0+w*16..+15. KV tiles of 64 keys; V stored transposed in LDS.
__global__ __launch_bounds__(256) void attn_mfma(const u16* __restrict__ qkv, u16* __restrict__ obuf){
  __shared__ u16 Ks[64][72];        // [key][d]
  __shared__ u16 Vt[64][72];        // [d][key]   (transposed V)
  __shared__ u16 Ps[4][16][72];     // per-wave P tile [q][key]
  int t = threadIdx.x;
  int w = t >> 6, l = t & 63;
  int lr = l & 15, lg = l >> 4;
  int bh = blockIdx.y;
  int b = bh / NHEAD, h = bh % NHEAD;
  int q0 = blockIdx.x * 64;

  // Q fragments (scaled by 1/8 = D^-0.5, exact in bf16)
  bf16x8 qf[2];
  {
    const u16* qp = qkv + (size_t)(b * NNCTX + q0 + w * 16 + lr) * 1152 + h * 64;
    #pragma unroll
    for (int c = 0; c < 2; c++){
      U8 r; r.u = *(const uint4*)(qp + c * 32 + lg * 8);
      #pragma unroll
      for (int j = 0; j < 8; j++) r.s[j] = f2bf(bf2f(r.s[j]) * 0.125f);
      qf[c] = r.v;
    }
  }
  f32x4 oacc[4] = {};               // [d-tile]; reg r = q-row lg*4+r, col d = lr+16*dt
  float m_r[4] = { -3.4e38f, -3.4e38f, -3.4e38f, -3.4e38f };
  float l_r[4] = {};

  const size_t kvrow = (size_t)(b * NNCTX) * 1152 + h * 64;

  for (int kt = 0; kt < 32; kt++){
    __syncthreads();
    { // stage K [64][64]: thread -> key=t>>2, d-chunk=(t&3)*16
      int key = t >> 2, dp = (t & 3) * 16;
      const u16* kp = qkv + kvrow + (size_t)(kt * 64 + key) * 1152 + 384 + dp;
      *(uint4*)&Ks[key][dp]     = *(const uint4*)kp;
      *(uint4*)&Ks[key][dp + 8] = *(const uint4*)(kp + 8);
    }
    { // stage V transposed: thread -> key=l, d-chunk=w*16 (conflict-free row writes)
      int key = l, dp = w * 16;
      const u16* vp = qkv + kvrow + (size_t)(kt * 64 + key) * 1152 + 768 + dp;
      U8 v0, v1; v0.u = *(const uint4*)vp; v1.u = *(const uint4*)(vp + 8);
      #pragma unroll
      for (int j = 0; j < 8; j++){ Vt[dp + j][key] = v0.s[j]; Vt[dp + 8 + j][key] = v1.s[j]; }
    }
    __syncthreads();

    // S = Q K^T : 4 key-tiles x 2 k-chunks
    f32x4 s[4] = {};
    #pragma unroll
    for (int ti = 0; ti < 4; ti++){
      #pragma unroll
      for (int c = 0; c < 2; c++){
        bf16x8 kf = *(const bf16x8*)&Ks[ti * 16 + lr][c * 32 + lg * 8];
        s[ti] = __builtin_amdgcn_mfma_f32_16x16x32_bf16(qf[c], kf, s[ti], 0, 0, 0);
      }
    }
    // online softmax per q-row r (16 lanes sharing lg hold 4 keys each)
    float alpha[4];
    #pragma unroll
    for (int r = 0; r < 4; r++){
      float mt = fmaxf(fmaxf(s[0][r], s[1][r]), fmaxf(s[2][r], s[3][r]));
      mt = fmaxf(mt, __shfl_xor(mt, 1));
      mt = fmaxf(mt, __shfl_xor(mt, 2));
      mt = fmaxf(mt, __shfl_xor(mt, 4));
      mt = fmaxf(mt, __shfl_xor(mt, 8));
      float mn = fmaxf(m_r[r], mt);
      float p0 = __expf(s[0][r] - mn), p1 = __expf(s[1][r] - mn);
      float p2 = __expf(s[2][r] - mn), p3 = __expf(s[3][r] - mn);
      float ps = p0 + p1 + p2 + p3;
      ps += __shfl_xor(ps, 1);
      ps += __shfl_xor(ps, 2);
      ps += __shfl_xor(ps, 4);
      ps += __shfl_xor(ps, 8);
      alpha[r] = __expf(m_r[r] - mn);
      l_r[r] = l_r[r] * alpha[r] + ps;
      m_r[r] = mn;
      int qr = lg * 4 + r;
      Ps[w][qr][lr]      = f2bf(p0);
      Ps[w][qr][lr + 16] = f2bf(p1);
      Ps[w][qr][lr + 32] = f2bf(p2);
      Ps[w][qr][lr + 48] = f2bf(p3);
    }
    #pragma unroll
    for (int dt = 0; dt < 4; dt++)
      #pragma unroll
      for (int r = 0; r < 4; r++) oacc[dt][r] *= alpha[r];

    // O += P V : A = P[q][key] (wave-private LDS), B = Vt[d][key]
    #pragma unroll
    for (int c = 0; c < 2; c++){
      bf16x8 pf = *(const bf16x8*)&Ps[w][lr][c * 32 + lg * 8];
      #pragma unroll
      for (int dt = 0; dt < 4; dt++){
        bf16x8 vf = *(const bf16x8*)&Vt[dt * 16 + lr][c * 32 + lg * 8];
        oacc[dt] = __builtin_amdgcn_mfma_f32_16x16x32_bf16(pf, vf, oacc[dt], 0, 0, 0);
      }
    }
  }
  // epilogue
  #pragma unroll
  for (int r = 0; r < 4; r++){
    float inv = 1.0f / l_r[r];
    int row = b * NNCTX + q0 + w * 16 + lg * 4 + r;
    u16* op = obuf + (size_t)row * CCH + h * 64 + lr;
    op[0]  = f2bf(oacc[0][r] * inv);
    op[16] = f2bf(oacc[1][r] * inv);
    op[32] = f2bf(oacc[2][r] * inv);
    op[48] = f2bf(oacc[3][r] * inv);
  }
}

extern "C" void kernel_launch(void* const* d_in, const int* in_sizes, int n_in,
                              void* d_out, int out_size, void* d_ws, size_t ws_size,
                              hipStream_t stream){
  const float* x      = (const float*)d_in[0];
  const float* ln1_g  = (const float*)d_in[1];
  const float* ln1_b  = (const float*)d_in[2];
  const float* w_qkv  = (const float*)d_in[3];
  const float* w_proj = (const float*)d_in[4];
  const float* b_proj = (const float*)d_in[5];
  const float* ln2_g  = (const float*)d_in[6];
  const float* ln2_b  = (const float*)d_in[7];
  const float* w_fc1  = (const float*)d_in[8];
  const float* b_fc1  = (const float*)d_in[9];
  const float* w_fc2  = (const float*)d_in[10];
  const float* b_fc2  = (const float*)d_in[11];
  float* out = (float*)d_out;

  u16* ws = (u16*)d_ws;
  u16* wqkv_bf  = ws;                       // 384*1152 = 442368
  u16* wproj_bf = wqkv_bf + 442368;         // 384*384  = 147456
  u16* wfc1_bf  = wproj_bf + 147456;        // 384*1536 = 589824
  u16* wfc2_bf  = wfc1_bf + 589824;         // 1536*384 = 589824
  u16* h_bf     = wfc2_bf + 589824;         // 8192*384 = 3145728 (reused as h2)
  u16* qkv_bf   = h_bf + 3145728;           // 8192*1152 = 9437184
  u16* o_bf     = qkv_bf + 9437184;         // 8192*384 = 3145728
  u16* m_bf     = qkv_bf;                   // 8192*1536 (reuses qkv+o after proj)

  cast_kernel<<<(442368 + 255) / 256, 256, 0, stream>>>(w_qkv,  wqkv_bf,  442368);
  cast_kernel<<<(147456 + 255) / 256, 256, 0, stream>>>(w_proj, wproj_bf, 147456);
  cast_kernel<<<(589824 + 255) / 256, 256, 0, stream>>>(w_fc1,  wfc1_bf,  589824);
  cast_kernel<<<(589824 + 255) / 256, 256, 0, stream>>>(w_fc2,  wfc2_bf,  589824);

  // LN1 -> h (bf16)
  ln_kernel<<<8192, 128, 0, stream>>>(x, ln1_g, ln1_b, h_bf);
  // QKV = h @ w_qkv  [8192,1152] bf16
  gemm_bf16<0><<<dim3(18, 128), 256, 0, stream>>>(h_bf, wqkv_bf, 384, 1152, qkv_bf, nullptr, nullptr, nullptr);
  // attention -> o (bf16)
  attn_mfma<<<dim3(32, 24), 256, 0, stream>>>(qkv_bf, o_bf);
  // x1 = x + o @ w_proj + b_proj  (fp32, into d_out)
  gemm_bf16<1><<<dim3(6, 128), 256, 0, stream>>>(o_bf, wproj_bf, 384, 384, nullptr, b_proj, x, out);
  // LN2 -> h2 (bf16, reuse h)
  ln_kernel<<<8192, 128, 0, stream>>>(out, ln2_g, ln2_b, h_bf);
  // m = gelu(h2 @ w_fc1 + b_fc1)  bf16
  gemm_bf16<2><<<dim3(24, 128), 256, 0, stream>>>(h_bf, wfc1_bf, 384, 1536, m_bf, b_fc1, nullptr, nullptr);
  // out = x1 + m @ w_fc2 + b_fc2  (fp32, in-place on d_out)
  gemm_bf16<1><<<dim3(6, 128), 256, 0, stream>>>(m_bf, wfc2_bf, 1536, 384, nullptr, b_fc2, out, out);
}

// Round 3
// 229.970 us; speedup vs baseline: 3.6727x; 1.2797x over previous
//
#include <hip/hip_runtime.h>

typedef __bf16 bf16x8 __attribute__((ext_vector_type(8)));
typedef float f32x4 __attribute__((ext_vector_type(4)));
typedef unsigned short u16;
typedef unsigned int u32;

#define BB 4
#define NNCTX 2048
#define CCH 384
#define NHEAD 6
#define DHEAD 64
#define HIDDIM 1536

__device__ __forceinline__ u16 f2bf(float f){
  u32 u = __builtin_bit_cast(u32, f);
  u = u + 0x7fffu + ((u >> 16) & 1u);
  return (u16)(u >> 16);
}
__device__ __forceinline__ float bf2f(u16 h){
  u32 u = ((u32)h) << 16;
  return __builtin_bit_cast(float, u);
}

union U8 { uint4 u; u16 s[8]; bf16x8 v; };

// Merged weight cast: 442368+147456+589824+589824 = 1769472 elems = 442368 float4 units = 1728 blocks exactly.
__global__ __launch_bounds__(256) void cast_all(const float* __restrict__ w0, const float* __restrict__ w1,
    const float* __restrict__ w2, const float* __restrict__ w3,
    u16* __restrict__ o0, u16* __restrict__ o1, u16* __restrict__ o2, u16* __restrict__ o3){
  int i = blockIdx.x * 256 + threadIdx.x;
  const int n0 = 442368/4, n1 = 147456/4, n2 = 589824/4;
  const float* src; u16* dst; int j;
  if (i < n0){ src = w0; dst = o0; j = i; }
  else if (i < n0 + n1){ src = w1; dst = o1; j = i - n0; }
  else if (i < n0 + n1 + n2){ src = w2; dst = o2; j = i - n0 - n1; }
  else { src = w3; dst = o3; j = i - n0 - n1 - n2; }
  float4 v = ((const float4*)src)[j];
  ushort4 o; o.x = f2bf(v.x); o.y = f2bf(v.y); o.z = f2bf(v.z); o.w = f2bf(v.w);
  ((ushort4*)dst)[j] = o;
}

// One block per row (C=384), 128 threads: each handles 3 elements.
__global__ __launch_bounds__(128) void ln_kernel(const float* __restrict__ x, const float* __restrict__ g,
                                                 const float* __restrict__ bb, u16* __restrict__ out){
  int row = blockIdx.x, t = threadIdx.x;
  const float* xr = x + (size_t)row * CCH;
  float v0 = xr[t], v1 = xr[t + 128], v2 = xr[t + 256];
  float s = v0 + v1 + v2;
  float q = v0 * v0 + v1 * v1 + v2 * v2;
  #pragma unroll
  for (int o = 32; o; o >>= 1){ s += __shfl_down(s, o); q += __shfl_down(q, o); }
  __shared__ float sh[4];
  if ((t & 63) == 0){ int w = t >> 6; sh[w * 2] = s; sh[w * 2 + 1] = q; }
  __syncthreads();
  float sum = sh[0] + sh[2], ssq = sh[1] + sh[3];
  float mu = sum * (1.0f / 384.0f);
  float rstd = rsqrtf(ssq * (1.0f / 384.0f) - mu * mu + 1e-5f);
  size_t base = (size_t)row * CCH;
  out[base + t]       = f2bf((v0 - mu) * rstd * g[t]       + bb[t]);
  out[base + t + 128] = f2bf((v1 - mu) * rstd * g[t + 128] + bb[t + 128]);
  out[base + t + 256] = f2bf((v2 - mu) * rstd * g[t + 256] + bb[t + 256]);
}

// Tiled bf16 MFMA GEMM: C[M,Nn] = A[M,K] @ B[K,Nn]. 64x64 tile, 256 threads (4 waves, 2x2 of 32x32).
// EPI 0: store bf16. EPI 1: fp32 out = resid + acc + bias. EPI 2: bf16 out = gelu(acc + bias).
// DBUF 1: double-buffered LDS + reg prefetch, 1 barrier/iter (for grid-limited launches).
template<int EPI, int DBUF>
__global__ __launch_bounds__(256) void gemm_bf16(const u16* __restrict__ A, const u16* __restrict__ Bm,
    int K, int Nn, u16* __restrict__ outb, const float* __restrict__ bias,
    const float* __restrict__ resid, float* __restrict__ outf)
{
  __shared__ u16 As[DBUF + 1][64][68];   // stride 136B: uniform 4/bank on b128 frag reads
  __shared__ u16 Bs[DBUF + 1][64][68];   // [n][k] transposed
  int t = threadIdx.x;
  int bm = blockIdx.y * 64, bn = blockIdx.x * 64;
  int l = t & 63, w = t >> 6;
  int wm = (w >> 1) * 32, wn = (w & 1) * 32;
  f32x4 acc[2][2] = {};
  int ar0 = t >> 3, ac0 = (t & 7) * 8;
  uint4 la0, la1, lb0, lb1;
  auto LOADG = [&](int k0){
    la0 = *(const uint4*)&A[(size_t)(bm + ar0) * K + k0 + ac0];
    la1 = *(const uint4*)&A[(size_t)(bm + ar0 + 32) * K + k0 + ac0];
    lb0 = *(const uint4*)&Bm[(size_t)(k0 + ar0) * Nn + bn + ac0];
    lb1 = *(const uint4*)&Bm[(size_t)(k0 + ar0 + 32) * Nn + bn + ac0];
  };
  auto WRITEL = [&](int bf){
    *(uint4*)&As[bf][ar0][ac0]      = la0;
    *(uint4*)&As[bf][ar0 + 32][ac0] = la1;
    const u16* p0 = (const u16*)&lb0;
    const u16* p1 = (const u16*)&lb1;
    #pragma unroll
    for (int j = 0; j < 8; j++){ Bs[bf][ac0 + j][ar0] = p0[j]; Bs[bf][ac0 + j][ar0 + 32] = p1[j]; }
  };
  auto COMPUTE = [&](int bf){
    #pragma unroll
    for (int ks = 0; ks < 2; ks++){
      int kb = ks * 32 + (l >> 4) * 8;
      bf16x8 a0  = *(const bf16x8*)&As[bf][wm + (l & 15)][kb];
      bf16x8 a1  = *(const bf16x8*)&As[bf][wm + 16 + (l & 15)][kb];
      bf16x8 bb0 = *(const bf16x8*)&Bs[bf][wn + (l & 15)][kb];
      bf16x8 bb1 = *(const bf16x8*)&Bs[bf][wn + 16 + (l & 15)][kb];
      acc[0][0] = __builtin_amdgcn_mfma_f32_16x16x32_bf16(a0, bb0, acc[0][0], 0, 0, 0);
      acc[0][1] = __builtin_amdgcn_mfma_f32_16x16x32_bf16(a0, bb1, acc[0][1], 0, 0, 0);
      acc[1][0] = __builtin_amdgcn_mfma_f32_16x16x32_bf16(a1, bb0, acc[1][0], 0, 0, 0);
      acc[1][1] = __builtin_amdgcn_mfma_f32_16x16x32_bf16(a1, bb1, acc[1][1], 0, 0, 0);
    }
  };
  if constexpr (DBUF){
    int nk = K >> 6;
    LOADG(0);
    WRITEL(0);
    __syncthreads();
    for (int ki = 0; ki < nk; ki++){
      int cur = ki & 1;
      if (ki + 1 < nk) LOADG((ki + 1) << 6);
      COMPUTE(cur);
      if (ki + 1 < nk) WRITEL(cur ^ 1);
      __syncthreads();
    }
  } else {
    for (int k0 = 0; k0 < K; k0 += 64){
      __syncthreads();
      LOADG(k0);
      WRITEL(0);
      __syncthreads();
      COMPUTE(0);
    }
  }
  #pragma unroll
  for (int mi = 0; mi < 2; mi++)
  #pragma unroll
  for (int ni = 0; ni < 2; ni++)
  #pragma unroll
  for (int r = 0; r < 4; r++){
    int row = bm + wm + mi * 16 + ((l >> 4) << 2) + r;
    int col = bn + wn + ni * 16 + (l & 15);
    size_t idx = (size_t)row * Nn + col;
    float v = acc[mi][ni][r];
    if (EPI == 0){
      outb[idx] = f2bf(v);
    } else if (EPI == 1){
      outf[idx] = resid[idx] + v + bias[col];
    } else {
      v += bias[col];
      v = 0.5f * v * (1.0f + erff(v * 0.70710678118f));
      outb[idx] = f2bf(v);
    }
  }
}

// MFMA flash attention, double-buffered + reg-prefetched, 1 barrier/iter.
// Block = 256 threads (4 waves) = one (b,h), 64 q-rows; wave w owns q-rows w*16..+15.
// Key storage permutation j(k) = (k&15)*4 + (k>>4) applied identically to P and Vt
// (the PV k-sum is order-invariant), making P writes contiguous b64 stores.
// Q pre-scaled by 0.125*log2(e): softmax runs in exp2 domain (base-invariant).
__global__ __launch_bounds__(256) void attn_mfma(const u16* __restrict__ qkv, u16* __restrict__ obuf){
  __shared__ u16 Ks[2][64][68];        // [key][d]
  __shared__ u16 Vt[2][64][68];        // [d][j]   (transposed + key-permuted V)
  __shared__ u16 Ps[4][16][68];        // per-wave P [q][j]
  int t = threadIdx.x;
  int w = t >> 6, l = t & 63;
  int lr = l & 15, lg = l >> 4;
  int bh = blockIdx.y;
  int b = bh / NHEAD, h = bh % NHEAD;
  int q0 = blockIdx.x * 64;

  // Q fragments scaled by 0.125 * log2(e)
  const float QS = 0.1803368801111716f;
  bf16x8 qf[2];
  {
    const u16* qp = qkv + (size_t)(b * NNCTX + q0 + w * 16 + lr) * 1152 + h * 64;
    #pragma unroll
    for (int c = 0; c < 2; c++){
      U8 r; r.u = *(const uint4*)(qp + c * 32 + lg * 8);
      #pragma unroll
      for (int j = 0; j < 8; j++) r.s[j] = f2bf(bf2f(r.s[j]) * QS);
      qf[c] = r.v;
    }
  }
  f32x4 oacc[4] = {};
  float m_r[4] = { -3.4e38f, -3.4e38f, -3.4e38f, -3.4e38f };
  float l_r[4] = {};

  const size_t kvrow = (size_t)(b * NNCTX) * 1152 + h * 64;
  int key4 = t >> 2, dp4 = (t & 3) * 16;       // K staging: 2 uint4 per thread
  int vj = (l & 15) * 4 + (l >> 4);            // V staging: permuted column for key=l
  int vdp = w * 16;

  uint4 kra, krb, vra, vrb;
  auto LOADT = [&](int kt){
    const u16* kp = qkv + kvrow + (size_t)(kt * 64 + key4) * 1152 + 384 + dp4;
    kra = *(const uint4*)kp;
    krb = *(const uint4*)(kp + 8);
    const u16* vp = qkv + kvrow + (size_t)(kt * 64 + l) * 1152 + 768 + vdp;
    vra = *(const uint4*)vp;
    vrb = *(const uint4*)(vp + 8);
  };
  auto WRITET = [&](int bf){
    *(uint4*)&Ks[bf][key4][dp4]     = kra;
    *(uint4*)&Ks[bf][key4][dp4 + 8] = krb;
    U8 v0, v1; v0.u = vra; v1.u = vrb;
    #pragma unroll
    for (int j = 0; j < 8; j++){ Vt[bf][vdp + j][vj] = v0.s[j]; Vt[bf][vdp + 8 + j][vj] = v1.s[j]; }
  };

  LOADT(0);
  WRITET(0);
  __syncthreads();

  for (int kt = 0; kt < 32; kt++){
    int cur = kt & 1;
    if (kt + 1 < 32) LOADT(kt + 1);

    // S = Q K^T (log2 domain)
    f32x4 s[4] = {};
    #pragma unroll
    for (int ti = 0; ti < 4; ti++){
      #pragma unroll
      for (int c = 0; c < 2; c++){
        bf16x8 kf = *(const bf16x8*)&Ks[cur][ti * 16 + lr][c * 32 + lg * 8];
        s[ti] = __builtin_amdgcn_mfma_f32_16x16x32_bf16(qf[c], kf, s[ti], 0, 0, 0);
      }
    }
    // row maxes
    float mx[4];
    #pragma unroll
    for (int r = 0; r < 4; r++){
      float mt = fmaxf(fmaxf(s[0][r], s[1][r]), fmaxf(s[2][r], s[3][r]));
      mt = fmaxf(mt, __shfl_xor(mt, 1));
      mt = fmaxf(mt, __shfl_xor(mt, 2));
      mt = fmaxf(mt, __shfl_xor(mt, 4));
      mt = fmaxf(mt, __shfl_xor(mt, 8));
      mx[r] = mt;
    }
    bool grow = (mx[0] > m_r[0]) || (mx[1] > m_r[1]) || (mx[2] > m_r[2]) || (mx[3] > m_r[3]);
    if (__any(grow)){
      #pragma unroll
      for (int r = 0; r < 4; r++){
        float mn = fmaxf(m_r[r], mx[r]);
        float a = __builtin_exp2f(m_r[r] - mn);
        l_r[r] *= a;
        m_r[r] = mn;
        #pragma unroll
        for (int dt = 0; dt < 4; dt++) oacc[dt][r] *= a;
      }
    }
    // P = exp2(S - m), packed b64 writes at permuted-contiguous [q][lr*4..+3]
    #pragma unroll
    for (int r = 0; r < 4; r++){
      float p0 = __builtin_exp2f(s[0][r] - m_r[r]);
      float p1 = __builtin_exp2f(s[1][r] - m_r[r]);
      float p2 = __builtin_exp2f(s[2][r] - m_r[r]);
      float p3 = __builtin_exp2f(s[3][r] - m_r[r]);
      float ps = p0 + p1 + p2 + p3;
      ps += __shfl_xor(ps, 1);
      ps += __shfl_xor(ps, 2);
      ps += __shfl_xor(ps, 4);
      ps += __shfl_xor(ps, 8);
      l_r[r] += ps;
      uint2 pk;
      pk.x = (u32)f2bf(p0) | ((u32)f2bf(p1) << 16);
      pk.y = (u32)f2bf(p2) | ((u32)f2bf(p3) << 16);
      *(uint2*)&Ps[w][lg * 4 + r][lr * 4] = pk;
    }
    // O += P V  (j-sum over permuted order, consistent on both operands)
    #pragma unroll
    for (int c = 0; c < 2; c++){
      bf16x8 pf = *(const bf16x8*)&Ps[w][lr][c * 32 + lg * 8];
      #pragma unroll
      for (int dt = 0; dt < 4; dt++){
        bf16x8 vf = *(const bf16x8*)&Vt[cur][dt * 16 + lr][c * 32 + lg * 8];
        oacc[dt] = __builtin_amdgcn_mfma_f32_16x16x32_bf16(pf, vf, oacc[dt], 0, 0, 0);
      }
    }
    if (kt + 1 < 32) WRITET(cur ^ 1);
    __syncthreads();
  }
  // epilogue
  #pragma unroll
  for (int r = 0; r < 4; r++){
    float inv = 1.0f / l_r[r];
    int row = b * NNCTX + q0 + w * 16 + lg * 4 + r;
    u16* op = obuf + (size_t)row * CCH + h * 64 + lr;
    op[0]  = f2bf(oacc[0][r] * inv);
    op[16] = f2bf(oacc[1][r] * inv);
    op[32] = f2bf(oacc[2][r] * inv);
    op[48] = f2bf(oacc[3][r] * inv);
  }
}

extern "C" void kernel_launch(void* const* d_in, const int* in_sizes, int n_in,
                              void* d_out, int out_size, void* d_ws, size_t ws_size,
                              hipStream_t stream){
  const float* x      = (const float*)d_in[0];
  const float* ln1_g  = (const float*)d_in[1];
  const float* ln1_b  = (const float*)d_in[2];
  const float* w_qkv  = (const float*)d_in[3];
  const float* w_proj = (const float*)d_in[4];
  const float* b_proj = (const float*)d_in[5];
  const float* ln2_g  = (const float*)d_in[6];
  const float* ln2_b  = (const float*)d_in[7];
  const float* w_fc1  = (const float*)d_in[8];
  const float* b_fc1  = (const float*)d_in[9];
  const float* w_fc2  = (const float*)d_in[10];
  const float* b_fc2  = (const float*)d_in[11];
  float* out = (float*)d_out;

  u16* ws = (u16*)d_ws;
  u16* wqkv_bf  = ws;                       // 384*1152 = 442368
  u16* wproj_bf = wqkv_bf + 442368;         // 384*384  = 147456
  u16* wfc1_bf  = wproj_bf + 147456;        // 384*1536 = 589824
  u16* wfc2_bf  = wfc1_bf + 589824;         // 1536*384 = 589824
  u16* h_bf     = wfc2_bf + 589824;         // 8192*384 = 3145728 (reused as h2)
  u16* qkv_bf   = h_bf + 3145728;           // 8192*1152 = 9437184
  u16* o_bf     = qkv_bf + 9437184;         // 8192*384 = 3145728
  u16* m_bf     = qkv_bf;                   // 8192*1536 (reuses qkv+o after proj)

  cast_all<<<1728, 256, 0, stream>>>(w_qkv, w_proj, w_fc1, w_fc2, wqkv_bf, wproj_bf, wfc1_bf, wfc2_bf);

  // LN1 -> h (bf16)
  ln_kernel<<<8192, 128, 0, stream>>>(x, ln1_g, ln1_b, h_bf);
  // QKV = h @ w_qkv  [8192,1152] bf16
  gemm_bf16<0, 0><<<dim3(18, 128), 256, 0, stream>>>(h_bf, wqkv_bf, 384, 1152, qkv_bf, nullptr, nullptr, nullptr);
  // attention -> o (bf16)
  attn_mfma<<<dim3(32, 24), 256, 0, stream>>>(qkv_bf, o_bf);
  // x1 = x + o @ w_proj + b_proj  (fp32, into d_out)
  gemm_bf16<1, 1><<<dim3(6, 128), 256, 0, stream>>>(o_bf, wproj_bf, 384, 384, nullptr, b_proj, x, out);
  // LN2 -> h2 (bf16, reuse h)
  ln_kernel<<<8192, 128, 0, stream>>>(out, ln2_g, ln2_b, h_bf);
  // m = gelu(h2 @ w_fc1 + b_fc1)  bf16
  gemm_bf16<2, 0><<<dim3(24, 128), 256, 0, stream>>>(h_bf, wfc1_bf, 384, 1536, m_bf, b_fc1, nullptr, nullptr);
  // out = x1 + m @ w_fc2 + b_fc2  (fp32, in-place on d_out)
  gemm_bf16<1, 1><<<dim3(6, 128), 256, 0, stream>>>(m_bf, wfc2_bf, 1536, 384, nullptr, b_fc2, out, out);
}